// Round 3
// baseline (208.706 us; speedup 1.0000x reference)
//
#include <hip/hip_runtime.h>
#include <math.h>

#define MROWS 32768   // B*T
#define DDIM  1024
#define EDIM  64
#define KC    32      // k-chunk held in VGPRs
#define NKC   (DDIM / KC)   // 32
#define ROWS_PER_WAVE 8
#define WAVES 4
#define TILEM (ROWS_PER_WAVE * WAVES)   // 32 rows per block

__global__ __launch_bounds__(256, 4)
void router_fused(const float* __restrict__ X,
                  const float* __restrict__ Wr_g,
                  const float* __restrict__ br_g,
                  const float* __restrict__ Wn_g,
                  const float* __restrict__ bn_g,
                  const float* __restrict__ U,
                  float* __restrict__ out)
{
    // accumulator planes: [route|noise][32 rows][64 experts]
    __shared__ float accL[2 * TILEM * EDIM];   // 16 KB

    const int t    = threadIdx.x;
    const int lane = t & 63;
    const int w    = __builtin_amdgcn_readfirstlane(t >> 6);   // wave id 0..3
    const int rowBase = blockIdx.x * TILEM;
    const int waveRow0 = rowBase + w * ROWS_PER_WAVE;          // uniform

    float* myAccR = accL + (w * ROWS_PER_WAVE) * EDIM;
    float* myAccN = accL + TILEM * EDIM + (w * ROWS_PER_WAVE) * EDIM;

    // zero-init acc planes (4096 floats, 4 float4 per thread)
#pragma unroll
    for (int q = 0; q < 4; ++q) {
        *(float4*)(accL + (q * 256 + t) * 4) = make_float4(0.f, 0.f, 0.f, 0.f);
    }
    __syncthreads();

    // ---- K loop: W chunk in VGPRs, wave-uniform A, acc RMW in wave-private LDS ----
    for (int kc = 0; kc < NKC; ++kc) {
        const int k0 = kc * KC;
        float wr[KC], wn[KC];
#pragma unroll
        for (int j = 0; j < KC; ++j) {
            wr[j] = Wr_g[(size_t)(k0 + j) * EDIM + lane];   // coalesced, L2-hot
            wn[j] = Wn_g[(size_t)(k0 + j) * EDIM + lane];
        }
#pragma unroll
        for (int r = 0; r < ROWS_PER_WAVE; ++r) {
            const float* ap = X + (size_t)(waveRow0 + r) * DDIM + k0;  // uniform addr
            float ar = myAccR[r * EDIM + lane];
            float an = myAccN[r * EDIM + lane];
#pragma unroll
            for (int q = 0; q < 4; ++q) {      // 4 sub-batches of 8 k
                float4 a0 = *(const float4*)(ap + q * 8);
                float4 a1 = *(const float4*)(ap + q * 8 + 4);
                float a[8] = {a0.x, a0.y, a0.z, a0.w, a1.x, a1.y, a1.z, a1.w};
#pragma unroll
                for (int j = 0; j < 8; ++j) {
                    ar = fmaf(a[j], wr[q * 8 + j], ar);
                    an = fmaf(a[j], wn[q * 8 + j], an);
                }
            }
            myAccR[r * EDIM + lane] = ar;
            myAccN[r * EDIM + lane] = an;
        }
    }

    // ---- epilogue: bias + softplus noise + wave-butterfly top-2 + writes ----
    const float br = br_g[lane];
    const float bn = bn_g[lane];

#pragma unroll
    for (int r = 0; r < ROWS_PER_WAVE; ++r) {
        const int row = waveRow0 + r;
        const float u = U[(size_t)row * EDIM + lane];
        const float lr = myAccR[r * EDIM + lane] + br;
        const float ln = myAccN[r * EDIM + lane] + bn;
        const float noisy = lr + u * log1pf(expf(ln));   // softplus

        // 64-lane butterfly top-2 with (value desc, index asc) ordering
        float m1 = noisy; int i1 = lane;
        float m2 = -INFINITY; int i2 = 64;
#pragma unroll
        for (int s = 1; s < 64; s <<= 1) {
            float om1 = __shfl_xor(m1, s);
            int   oi1 = __shfl_xor(i1, s);
            float om2 = __shfl_xor(m2, s);
            int   oi2 = __shfl_xor(i2, s);
            bool aw = (m1 > om1) || (m1 == om1 && i1 < oi1);
            float w1 = aw ? m1 : om1;  int wi1 = aw ? i1 : oi1;
            float c2a = aw ? m2 : om2; int c2ai = aw ? i2 : oi2;  // winner's 2nd
            float c2b = aw ? om1 : m1; int c2bi = aw ? oi1 : i1;  // loser's 1st
            bool bw = (c2b > c2a) || (c2b == c2a && c2bi < c2ai);
            m1 = w1; i1 = wi1;
            m2 = bw ? c2b : c2a;
            i2 = bw ? c2bi : c2ai;
        }

        const float e2  = expf(m2 - m1);
        const float inv = 1.0f / (1.0f + e2);
        const float p   = (lane == i1) ? inv : ((lane == i2) ? e2 * inv : 0.0f);
        out[(size_t)row * EDIM + lane] = p;                       // coalesced
        if (lane < 2) {
            out[(size_t)MROWS * EDIM + (size_t)row * 2 + lane] =
                (float)(lane == 0 ? i1 : i2);
        }
    }
}

extern "C" void kernel_launch(void* const* d_in, const int* in_sizes, int n_in,
                              void* d_out, int out_size, void* d_ws, size_t ws_size,
                              hipStream_t stream) {
    const float* X  = (const float*)d_in[0];  // mh_output [8,4096,1024]
    const float* Wr = (const float*)d_in[1];  // W_route   [1024,64]
    const float* br = (const float*)d_in[2];  // b_route   [64]
    const float* Wn = (const float*)d_in[3];  // W_noise   [1024,64]
    const float* bn = (const float*)d_in[4];  // b_noise   [64]
    const float* U  = (const float*)d_in[5];  // noise_u   [8,4096,64]
    (void)in_sizes; (void)n_in; (void)d_ws; (void)ws_size; // top_k=2 hardcoded
    router_fused<<<MROWS / TILEM, 256, 0, stream>>>(X, Wr, br, Wn, bn, U, (float*)d_out);
}

// Round 4
// 64.108 us; speedup vs baseline: 3.2555x; 3.2555x over previous
//
#include <hip/hip_runtime.h>
#include <math.h>

#define MROWS 32768   // B*T
#define DDIM  1024
#define EDIM  64
#define NCH   64      // K-chunks of 16
#define TILEM 64

typedef _Float16 f16x8 __attribute__((ext_vector_type(8)));
typedef float    f32x16 __attribute__((ext_vector_type(16)));

// ws layout per chunk c (4096 halves = 8 KB):
//   half index = c*4096 + p*2048 + nf*512 + lane*8 + j
//   (p = hi/lo plane, nf = 32-col group 0..3, lane = MFMA B-lane, j = k-elem)
// B-frag mapping for mfma_f32_32x32x16_f16: col = lane&31, k = (lane>>5)*8 + j
__global__ __launch_bounds__(256)
void convW_kernel(const float* __restrict__ Wr, const float* __restrict__ Wn,
                  unsigned short* __restrict__ ws) {
    int gid = blockIdx.x * 256 + threadIdx.x;   // 131072 total
    int c32 = gid & 31;
    int j   = (gid >> 5) & 7;
    int lhi = (gid >> 8) & 1;
    int nf  = (gid >> 9) & 3;
    int c   = gid >> 11;
    int lane = lhi * 32 + c32;
    int k   = c * 16 + lhi * 8 + j;
    int col = nf * 32 + c32;                    // global col: 0..63 route, 64..127 noise
    float w = (col < EDIM) ? Wr[k * EDIM + col] : Wn[k * EDIM + (col - EDIM)];
    _Float16 hi = (_Float16)w;
    _Float16 lo = (_Float16)((w - (float)hi) * 2048.0f);   // scaled: no fp16 denorm
    union { _Float16 h; unsigned short u; } cv;
    size_t base = (size_t)c * 4096 + nf * 512 + lane * 8 + j;
    cv.h = hi; ws[base]        = cv.u;
    cv.h = lo; ws[base + 2048] = cv.u;
}

__global__ __launch_bounds__(256)
void router_mfma(const float* __restrict__ X,
                 const unsigned short* __restrict__ WS,
                 const float* __restrict__ br_g,
                 const float* __restrict__ bn_g,
                 const float* __restrict__ U,
                 float* __restrict__ out)
{
    // GEMM phase: Ah [2buf][2p][64row][24h pad] = 12288 B, Bh [2buf][4096h] = 16384 B
    // Epilogue reuses smem as Lf[64][128] f32 = 32768 B
    __shared__ alignas(16) unsigned char smem[32768];
    unsigned short* Ah = (unsigned short*)smem;
    unsigned short* Bh = (unsigned short*)(smem + 12288);
    float*          Lf = (float*)smem;

    const int t    = threadIdx.x;
    const int lane = t & 63;
    const int wid  = t >> 6;
    const int wm   = wid >> 1;    // wave row-half (0,1): rows wm*32..+31
    const int wn   = wid & 1;     // wave col-half (0,1): cols wn*64..+63
    const int rowBase = blockIdx.x * TILEM;

    f32x16 acc0[2], acc1[2];
#pragma unroll
    for (int n = 0; n < 2; ++n)
#pragma unroll
        for (int i = 0; i < 16; ++i) { acc0[n][i] = 0.f; acc1[n][i] = 0.f; }

    // A staging map: thread -> (row, 4 consecutive k)
    const int arow = t >> 2;
    const int ak0  = (t & 3) * 4;
    const float* xsrc = X + (size_t)(rowBase + arow) * DDIM + ak0;

    auto convA = [&](float4 x, int buf) {
        union { _Float16 h[4]; uint2 v; } H, L;
        float xs[4] = {x.x, x.y, x.z, x.w};
#pragma unroll
        for (int i = 0; i < 4; ++i) {
            _Float16 hi = (_Float16)xs[i];
            H.h[i] = hi;
            L.h[i] = (_Float16)((xs[i] - (float)hi) * 2048.0f);
        }
        *(uint2*)(Ah + ((buf * 2 + 0) * 64 + arow) * 24 + ak0) = H.v;
        *(uint2*)(Ah + ((buf * 2 + 1) * 64 + arow) * 24 + ak0) = L.v;
    };

    auto compute = [&](int buf) {
        const unsigned short* Ab = Ah + (buf * 2) * 1536;
        const int aoff = (wm * 32 + (lane & 31)) * 24 + ((lane >> 5) * 8);
        f16x8 ahi = *(const f16x8*)(Ab + aoff);          // A: row=lane&31, k=(lane>>5)*8+j
        f16x8 alo = *(const f16x8*)(Ab + 1536 + aoff);
        const unsigned short* Bb = Bh + buf * 4096;
#pragma unroll
        for (int nfl = 0; nfl < 2; ++nfl) {
            const int nfg = wn * 2 + nfl;
            f16x8 bhi = *(const f16x8*)(Bb + nfg * 512 + lane * 8);
            f16x8 blo = *(const f16x8*)(Bb + 2048 + nfg * 512 + lane * 8);
            acc0[nfl] = __builtin_amdgcn_mfma_f32_32x32x16_f16(ahi, bhi, acc0[nfl], 0, 0, 0);
            acc1[nfl] = __builtin_amdgcn_mfma_f32_32x32x16_f16(ahi, blo, acc1[nfl], 0, 0, 0);
            acc1[nfl] = __builtin_amdgcn_mfma_f32_32x32x16_f16(alo, bhi, acc1[nfl], 0, 0, 0);
        }
    };

    // ---- prologue: stage chunk 0, prefetch X chunks 1,2 ----
    float4 x0 = *(const float4*)(xsrc);
    {
        uint4 b0 = *(const uint4*)(WS + t * 16);
        uint4 b1 = *(const uint4*)(WS + t * 16 + 8);
        convA(x0, 0);
        *(uint4*)(Bh + t * 16)     = b0;
        *(uint4*)(Bh + t * 16 + 8) = b1;
    }
    float4 xN = *(const float4*)(xsrc + 1 * 16);
    float4 xF = *(const float4*)(xsrc + 2 * 16);
    __syncthreads();

#define ITER(C, BUF, XN_, XF_)                                                 \
    {                                                                          \
        uint4 b0{}, b1{};                                                      \
        if ((C) + 1 < NCH) {                                                   \
            const unsigned short* wp = WS + (size_t)((C) + 1) * 4096 + t * 16; \
            b0 = *(const uint4*)(wp);                                          \
            b1 = *(const uint4*)(wp + 8);                                      \
        }                                                                      \
        compute(BUF);                                                          \
        if ((C) + 1 < NCH) {                                                   \
            convA(XN_, (BUF) ^ 1);                                             \
            *(uint4*)(Bh + ((BUF) ^ 1) * 4096 + t * 16)     = b0;              \
            *(uint4*)(Bh + ((BUF) ^ 1) * 4096 + t * 16 + 8) = b1;              \
        }                                                                      \
        if ((C) + 3 < NCH) XN_ = *(const float4*)(xsrc + ((C) + 3) * 16);      \
        __syncthreads();                                                       \
    }

    for (int c = 0; c < NCH; c += 2) {
        ITER(c,     0, xN, xF);
        ITER(c + 1, 1, xF, xN);
    }
#undef ITER

    // ---- combine hi/lo accumulators, write logits tile to LDS ----
    // C/D layout (32x32): col = lane&31, row = (reg&3) + 8*(reg>>2) + 4*(lane>>5)
    const float inv2048 = 1.0f / 2048.0f;
#pragma unroll
    for (int nfl = 0; nfl < 2; ++nfl) {
#pragma unroll
        for (int reg = 0; reg < 16; ++reg) {
            float v = acc0[nfl][reg] + acc1[nfl][reg] * inv2048;
            int rl  = (reg & 3) + ((reg >> 2) << 3) + ((lane >> 5) << 2);
            int row = wm * 32 + rl;
            int col = wn * 64 + nfl * 32 + (lane & 31);
            Lf[row * 128 + col] = v;
        }
    }
    __syncthreads();

    // ---- bias + softplus-noise + butterfly top-2 + writes (16 rows per wave) ----
    const float brv = br_g[lane];
    const float bnv = bn_g[lane];
#pragma unroll 4
    for (int r = 0; r < 16; ++r) {
        int row  = wid * 16 + r;
        int grow = rowBase + row;
        float lr = Lf[row * 128 + lane] + brv;
        float ln = Lf[row * 128 + 64 + lane] + bnv;
        float u  = U[(size_t)grow * EDIM + lane];
        float noisy = lr + u * log1pf(expf(ln));

        float m1 = noisy; int i1 = lane;
        float m2 = -INFINITY; int i2 = 64;
#pragma unroll
        for (int s = 1; s < 64; s <<= 1) {
            float om1 = __shfl_xor(m1, s);
            int   oi1 = __shfl_xor(i1, s);
            float om2 = __shfl_xor(m2, s);
            int   oi2 = __shfl_xor(i2, s);
            bool aw = (m1 > om1) || (m1 == om1 && i1 < oi1);
            float w1  = aw ? m1 : om1;  int wi1  = aw ? i1 : oi1;
            float c2a = aw ? m2 : om2;  int c2ai = aw ? i2 : oi2;
            float c2b = aw ? om1 : m1;  int c2bi = aw ? oi1 : i1;
            bool bw = (c2b > c2a) || (c2b == c2a && c2bi < c2ai);
            m1 = w1; i1 = wi1;
            m2 = bw ? c2b : c2a;
            i2 = bw ? c2bi : c2ai;
        }
        float e2  = expf(m2 - m1);
        float inv = 1.0f / (1.0f + e2);
        float p   = (lane == i1) ? inv : ((lane == i2) ? e2 * inv : 0.0f);
        out[(size_t)grow * EDIM + lane] = p;
        if (lane < 2)
            out[(size_t)MROWS * EDIM + (size_t)grow * 2 + lane] =
                (float)(lane == 0 ? i1 : i2);
    }
}

extern "C" void kernel_launch(void* const* d_in, const int* in_sizes, int n_in,
                              void* d_out, int out_size, void* d_ws, size_t ws_size,
                              hipStream_t stream) {
    const float* X  = (const float*)d_in[0];  // mh_output [8,4096,1024]
    const float* Wr = (const float*)d_in[1];  // W_route   [1024,64]
    const float* br = (const float*)d_in[2];  // b_route   [64]
    const float* Wn = (const float*)d_in[3];  // W_noise   [1024,64]
    const float* bn = (const float*)d_in[4];  // b_noise   [64]
    const float* U  = (const float*)d_in[5];  // noise_u   [8,4096,64]
    (void)in_sizes; (void)n_in; (void)ws_size; // needs 512 KB of d_ws
    unsigned short* ws16 = (unsigned short*)d_ws;
    convW_kernel<<<512, 256, 0, stream>>>(Wr, Wn, ws16);
    router_mfma<<<MROWS / TILEM, 256, 0, stream>>>(X, ws16, br, bn, U, (float*)d_out);
}